// Round 9
// baseline (103.873 us; speedup 1.0000x reference)
//
#include <hip/hip_runtime.h>

// GAM forward: 64 per-feature MLPs 1->16->16->16->1 (ELU), pred = out@Wp+bp.
// R1: row-major lane=sample access -> 250x RMW blowup. Fixed: transposed ws.
// R2/R5: pointer-cast local arrays -> scratch spill. Fixed: reg-friendly state.
// R6: LDS eliminated via wave-uniform s_load weights -> 82us, VALUBusy 79%.
// R7: pk-math at SPT=4 -> busy 65->57us BUT occupancy 46->24% (1024 blocks,
//   VGPR 80) -> net 88us. Lesson: pk win < occupancy loss at fat threads.
// R8: pk-math at SPT=2 (one v2f pair), FGF=4 -> 2048 blocks = 8 blk/CU =
//   full residency like R6; + next-feature x prefetch to break the per-
//   feature load->use serial chain.
// R9: R8 was an infra failure (UnresponsiveContainer) — resubmitting unchanged.

#define BLK 256
#define FGF 4       // features per block (fast path)
#define FG 8        // features per block (fallback path)
#define DTOT 64

typedef float v2f __attribute__((ext_vector_type(2)));

__device__ __forceinline__ v2f mul2(float s, v2f v) {
    v2f w = {s, s};
    return w * v;                       // v_pk_mul_f32
}
__device__ __forceinline__ v2f fma2(float s, v2f h, v2f a) {
    v2f w = {s, s};
    return __builtin_elementwise_fma(w, h, a);   // v_pk_fma_f32
}
__device__ __forceinline__ v2f elu2(v2f v) {
    // elu(v) = max(v,0) + min(exp(v)-1, 0)  (bit-identical to select form)
    v2f e;
    e.x = __expf(v.x);
    e.y = __expf(v.y);
    const v2f zero = {0.f, 0.f};
    const v2f one  = {1.f, 1.f};
    return __builtin_elementwise_max(v, zero) +
           __builtin_elementwise_min(e - one, zero);
}

__device__ __forceinline__ float elu_f(float v) {
    return v > 0.0f ? v : (__expf(v) - 1.0f);
}
__device__ __forceinline__ float4 mul4(float s, float4 w) {
    float4 r;
    r.x = s * w.x; r.y = s * w.y; r.z = s * w.z; r.w = s * w.w;
    return r;
}
__device__ __forceinline__ float4 fma4(float s, float4 w, float4 a) {
    a.x = fmaf(s, w.x, a.x); a.y = fmaf(s, w.y, a.y);
    a.z = fmaf(s, w.z, a.z); a.w = fmaf(s, w.w, a.w);
    return a;
}
__device__ __forceinline__ float4 elu4(float4 v) {
    float4 r;
    r.x = elu_f(v.x); r.y = elu_f(v.y); r.z = elu_f(v.z); r.w = elu_f(v.w);
    return r;
}
__device__ __forceinline__ float dot4(float4 a, float4 b) {
    return fmaf(a.x, b.x, fmaf(a.y, b.y, fmaf(a.z, b.z, a.w * b.w)));
}
__device__ __forceinline__ float4 zero4() {
    float4 r; r.x = 0.f; r.y = 0.f; r.z = 0.f; r.w = 0.f; return r;
}
__device__ __forceinline__ float getc(float4 v, int i) {
    switch (i & 3) {
        case 0: return v.x;
        case 1: return v.y;
        case 2: return v.z;
        default: return v.w;
    }
}
#define GET16(h0, h1, h2, h3, i) \
    getc((i) < 4 ? (h0) : (i) < 8 ? (h1) : (i) < 12 ? (h2) : (h3), (i))

// ---------------- fast path: transposed domain, SMEM weights, pk math -----

// x (N,64) -> xt (64,N). 64x64 tiles via LDS (pad 65 -> conflict-free).
__global__ __launch_bounds__(256) void transpose_in(
    const float* __restrict__ x, float* __restrict__ xt, int nsamp)
{
    __shared__ float t[64][65];
    const int s0 = blockIdx.x * 64;
    const int c = threadIdx.x & 63;
    const int r0 = threadIdx.x >> 6;
    for (int i = r0; i < 64; i += 4)
        t[i][c] = x[(size_t)(s0 + i) * DTOT + c];
    __syncthreads();
    for (int d = r0; d < 64; d += 4)
        xt[(size_t)d * nsamp + s0 + c] = t[c][d];
}

// SPT=2 (one v2f sample-pair/thread). No LDS; weights via uniform s_load.
// 2048 blocks -> 8 blocks/CU (full residency, zero tail).
__global__ __launch_bounds__(BLK) void gam_main_q(
    const float* __restrict__ xt, const float* __restrict__ W1,
    const float* __restrict__ W2, const float* __restrict__ W3,
    const float* __restrict__ W4, float* __restrict__ ot, int nsamp)
{
    const int tid = threadIdx.x;
    const int g = blockIdx.x & 15;       // feature group (16 groups of 4)
    const int chunk = blockIdx.x >> 4;   // sample chunk (512 samples)
    const int d0 = g * FGF;

    const int s0 = chunk * (BLK * 2) + tid;
    if (s0 >= nsamp) return;

    // prefetch feature d0's x pair
    v2f xcur;
    xcur.x = xt[(size_t)d0 * nsamp + s0];
    xcur.y = xt[(size_t)d0 * nsamp + s0 + BLK];

#pragma unroll 1
    for (int dd = 0; dd < FGF; ++dd) {
        const int d = d0 + dd;
        const size_t rowb = (size_t)d * nsamp;

        // issue next feature's x loads NOW; consumed next iteration
        const int dn = (dd + 1 < FGF) ? d + 1 : d;   // clamp: stays in-bounds
        v2f xnext;
        xnext.x = xt[(size_t)dn * nsamp + s0];
        xnext.y = xt[(size_t)dn * nsamp + s0 + BLK];

        // uniform per-feature weight bases (SALU arithmetic -> s_load)
        const float* w1p = W1 + (size_t)d * 1024 + d * 16;
        const float* w2p = W2 + (size_t)d * 16 * 1024 + d * 16;
        const float* w3p = W3 + (size_t)d * 16 * 1024 + d * 16;

        v2f hA[16];
        // layer 1: h = elu(x * w1_j)
#pragma unroll
        for (int j = 0; j < 16; ++j) {
            hA[j] = elu2(mul2(w1p[j], xcur));
        }

        // layer 2: acc_j = sum_i w[i][j] * h_i (i-sequential association)
        {
            v2f aA[16];
#pragma unroll
            for (int j = 0; j < 16; ++j) aA[j] = (v2f){0.f, 0.f};
#pragma unroll
            for (int i = 0; i < 16; ++i) {
                const float* wr = w2p + (size_t)i * 1024;
                const v2f hAi = hA[i];
#pragma unroll
                for (int j = 0; j < 16; ++j)
                    aA[j] = fma2(wr[j], hAi, aA[j]);
            }
#pragma unroll
            for (int j = 0; j < 16; ++j) hA[j] = elu2(aA[j]);
        }

        // layer 3
        {
            v2f aA[16];
#pragma unroll
            for (int j = 0; j < 16; ++j) aA[j] = (v2f){0.f, 0.f};
#pragma unroll
            for (int i = 0; i < 16; ++i) {
                const float* wr = w3p + (size_t)i * 1024;
                const v2f hAi = hA[i];
#pragma unroll
                for (int j = 0; j < 16; ++j)
                    aA[j] = fma2(wr[j], hAi, aA[j]);
            }
#pragma unroll
            for (int j = 0; j < 16; ++j) hA[j] = elu2(aA[j]);
        }

        // layer 4: two stride-2 partial chains (matches R6/R7 association)
        v2f o0 = {0.f, 0.f}, o1 = {0.f, 0.f};
#pragma unroll
        for (int i = 0; i < 16; i += 2) {
            const float wa = W4[(size_t)(d * 16 + i) * 64 + d];
            const float wb = W4[(size_t)(d * 16 + i + 1) * 64 + d];
            o0 = fma2(wa, hA[i], o0);
            o1 = fma2(wb, hA[i + 1], o1);
        }
        const v2f o = o0 + o1;
        ot[rowb + s0]       = o.x;      // lane-contiguous stores
        ot[rowb + s0 + BLK] = o.y;

        xcur = xnext;
    }
}

// ot (64,N) -> out (N,64) AND pred[s] = bp + sum_d ot[d][s]*Wp[d], fused.
__global__ __launch_bounds__(256) void finish(
    const float* __restrict__ ot, const float* __restrict__ Wp,
    const float* __restrict__ bp, float* __restrict__ out,
    float* __restrict__ pred, int nsamp)
{
    __shared__ float t[64][65];
    __shared__ float wps[64];
    const int s0 = blockIdx.x * 64;
    const int c = threadIdx.x & 63;
    const int r0 = threadIdx.x >> 6;
    if (threadIdx.x < 64) wps[threadIdx.x] = Wp[threadIdx.x];
    for (int d = r0; d < 64; d += 4)
        t[d][c] = ot[(size_t)d * nsamp + s0 + c];
    __syncthreads();
    for (int i = r0; i < 64; i += 4)
        out[(size_t)(s0 + i) * DTOT + c] = t[c][i];   // full 256B lines
    if (r0 == 0) {
        float p = bp[0];
#pragma unroll
        for (int d = 0; d < 64; ++d)
            p = fmaf(t[d][c], wps[d], p);   // banks (d+c)%32: conflict-free
        pred[s0 + c] = p;
    }
}

// ---------------- fallback (ws too small; LDS-staged, strided I/O) --------

__device__ __forceinline__ void stage_weights(
    int tid, int d0,
    const float* __restrict__ W1, const float* __restrict__ W2,
    const float* __restrict__ W3, const float* __restrict__ W4,
    float (*w1s)[16], float (*w2s)[16][16], float (*w3s)[16][16], float (*w4s)[16])
{
    if (tid < 128) {
        int dd = tid >> 4, j = tid & 15;
        int d = d0 + dd;
        w1s[dd][j] = W1[d * 1024 + d * 16 + j];
    } else {
        int t = tid - 128;
        int dd = t >> 4, i = t & 15;
        int d = d0 + dd;
        w4s[dd][i] = W4[(d * 16 + i) * 64 + d];
    }
    for (int idx = tid; idx < FG * 256; idx += BLK) {
        int dd = idx >> 8, r = idx & 255;
        int i = r >> 4, j = r & 15;
        int d = d0 + dd;
        size_t base = (size_t)(d * 16 + i) * 1024 + d * 16 + j;
        w2s[dd][i][j] = W2[base];
        w3s[dd][i][j] = W3[base];
    }
}

#define LAYER16L(ws)                                                       \
    {                                                                      \
        float4 a0 = zero4(), a1 = zero4(), a2 = zero4(), a3 = zero4();     \
        float4 b0 = zero4(), b1 = zero4(), b2 = zero4(), b3 = zero4();     \
        _Pragma("unroll")                                                  \
        for (int i = 0; i < 16; ++i) {                                     \
            const float hai = GET16(ha0, ha1, ha2, ha3, i);                \
            const float hbi = GET16(hb0, hb1, hb2, hb3, i);                \
            const float4* wp = (const float4*)((ws) + i * 16);             \
            const float4 q0 = wp[0], q1 = wp[1], q2 = wp[2], q3 = wp[3];   \
            a0 = fma4(hai, q0, a0); a1 = fma4(hai, q1, a1);                \
            a2 = fma4(hai, q2, a2); a3 = fma4(hai, q3, a3);                \
            b0 = fma4(hbi, q0, b0); b1 = fma4(hbi, q1, b1);                \
            b2 = fma4(hbi, q2, b2); b3 = fma4(hbi, q3, b3);                \
        }                                                                  \
        ha0 = elu4(a0); ha1 = elu4(a1); ha2 = elu4(a2); ha3 = elu4(a3);    \
        hb0 = elu4(b0); hb1 = elu4(b1); hb2 = elu4(b2); hb3 = elu4(b3);    \
    }

__global__ __launch_bounds__(BLK, 4) void gam_main_direct(
    const float* __restrict__ x, const float* __restrict__ W1,
    const float* __restrict__ W2, const float* __restrict__ W3,
    const float* __restrict__ W4, float* __restrict__ out, int nsamp)
{
    __shared__ float w1s[FG][16];
    __shared__ float w2s[FG][16][16];
    __shared__ float w3s[FG][16][16];
    __shared__ float w4s[FG][16];

    const int tid = threadIdx.x;
    const int g = blockIdx.x & 7;
    const int chunk = blockIdx.x >> 3;
    const int d0 = g * FG;

    stage_weights(tid, d0, W1, W2, W3, W4, w1s, w2s, w3s, w4s);
    __syncthreads();

    const int s0 = chunk * (BLK * 2) + tid;
    const int s1 = s0 + BLK;
    if (s0 >= nsamp) return;

    for (int dd = 0; dd < FG; ++dd) {
        const int d = d0 + dd;
        const float xv0 = x[(size_t)s0 * DTOT + d];
        const float xv1 = x[(size_t)s1 * DTOT + d];

        const float4* w1p = (const float4*)&w1s[dd][0];
        const float4 u0 = w1p[0], u1 = w1p[1], u2 = w1p[2], u3 = w1p[3];
        float4 ha0 = elu4(mul4(xv0, u0)), ha1 = elu4(mul4(xv0, u1));
        float4 ha2 = elu4(mul4(xv0, u2)), ha3 = elu4(mul4(xv0, u3));
        float4 hb0 = elu4(mul4(xv1, u0)), hb1 = elu4(mul4(xv1, u1));
        float4 hb2 = elu4(mul4(xv1, u2)), hb3 = elu4(mul4(xv1, u3));

        LAYER16L(&w2s[dd][0][0]);
        LAYER16L(&w3s[dd][0][0]);

        const float4* w4p = (const float4*)&w4s[dd][0];
        const float4 q0 = w4p[0], q1 = w4p[1], q2 = w4p[2], q3 = w4p[3];
        out[(size_t)s0 * DTOT + d] = (dot4(ha0, q0) + dot4(ha1, q1)) +
                                     (dot4(ha2, q2) + dot4(ha3, q3));
        out[(size_t)s1 * DTOT + d] = (dot4(hb0, q0) + dot4(hb1, q1)) +
                                     (dot4(hb2, q2) + dot4(hb3, q3));
    }
}

__global__ __launch_bounds__(BLK) void gam_pred_direct(
    const float* __restrict__ out, const float* __restrict__ Wp,
    const float* __restrict__ bp, float* __restrict__ pred, int nsamp)
{
    int gid = blockIdx.x * BLK + threadIdx.x;
    int wave = gid >> 6, lane = gid & 63;
    int sub = lane >> 4, li = lane & 15;
    int s = wave * 4 + sub;
    if (s >= nsamp) return;
    float4 wv = ((const float4*)Wp)[li];
    float4 v = ((const float4*)(out + (size_t)s * DTOT))[li];
    float p = v.x * wv.x + v.y * wv.y + v.z * wv.z + v.w * wv.w;
    p += __shfl_xor(p, 1);
    p += __shfl_xor(p, 2);
    p += __shfl_xor(p, 4);
    p += __shfl_xor(p, 8);
    if (li == 0) pred[s] = p + bp[0];
}

extern "C" void kernel_launch(void* const* d_in, const int* in_sizes, int n_in,
                              void* d_out, int out_size, void* d_ws, size_t ws_size,
                              hipStream_t stream) {
    const float* x  = (const float*)d_in[0];
    const float* W1 = (const float*)d_in[1];
    const float* W2 = (const float*)d_in[2];
    const float* W3 = (const float*)d_in[3];
    const float* W4 = (const float*)d_in[4];
    const float* Wp = (const float*)d_in[5];
    const float* bp = (const float*)d_in[6];

    const int nsamp = in_sizes[0] / DTOT;   // 65536
    float* pred = (float*)d_out;            // (N,1) first
    float* outm = pred + nsamp;             // (N,64) second

    const size_t need = (size_t)2 * nsamp * DTOT * sizeof(float);
    if (ws_size >= need && (nsamp % (BLK * 2)) == 0 && (nsamp % 64) == 0) {
        float* xt = (float*)d_ws;
        float* ot = xt + (size_t)nsamp * DTOT;
        transpose_in<<<dim3(nsamp / 64), dim3(256), 0, stream>>>(x, xt, nsamp);
        // nsamp/512 chunks x 16 groups (FGF=4) = 2048 blocks
        gam_main_q<<<dim3((nsamp / (BLK * 2)) * 16), dim3(BLK), 0, stream>>>(
            xt, W1, W2, W3, W4, ot, nsamp);
        finish<<<dim3(nsamp / 64), dim3(256), 0, stream>>>(
            ot, Wp, bp, outm, pred, nsamp);
    } else {
        int chunks = nsamp / (BLK * 2);
        gam_main_direct<<<dim3(chunks * 8), dim3(BLK), 0, stream>>>(
            x, W1, W2, W3, W4, outm, nsamp);
        int nthreads = (nsamp / 4) * 64;
        gam_pred_direct<<<dim3((nthreads + BLK - 1) / BLK), dim3(BLK), 0, stream>>>(
            outm, Wp, bp, pred, nsamp);
    }
}

// Round 11
// 88.922 us; speedup vs baseline: 1.1681x; 1.1681x over previous
//
#include <hip/hip_runtime.h>

// GAM forward: 64 per-feature MLPs 1->16->16->16->1 (ELU), pred = out@Wp+bp.
// R1: row-major lane=sample access -> 250x RMW blowup. Fixed: transposed ws.
// R2/R5: pointer-cast local arrays -> scratch spill. Fixed: reg-friendly state.
// R6: LDS eliminated via wave-uniform s_load weights -> 82us, VALUBusy 79%,
//   busy-time 65us, idle 21%.
// R7/R9: v_pk_fma_f32 NOT selected from v2f elementwise builtins (busy 65->77us
//   at same SPT) -> pk axis closed without disasm. Reverted to R6 scalar.
// R10: attack the 21% idle: FGF=2 -> 4096 blocks (2x grain count vs the exact
//   one-residency-round 2048) so drain/ramp backfills; + next-feature x
//   prefetch to break the per-feature load->use chain.
// R11: R10 was an infra failure (UnresponsiveContainer) — resubmitting unchanged.

#define BLK 256
#define FGF 2       // features per block (fast path)
#define FG 8        // features per block (fallback path)
#define DTOT 64

__device__ __forceinline__ float getc(float4 v, int i) {
    switch (i & 3) {
        case 0: return v.x;
        case 1: return v.y;
        case 2: return v.z;
        default: return v.w;
    }
}
// compile-time-folded 16-way select (i is a constant under #pragma unroll)
#define GET16(h0, h1, h2, h3, i) \
    getc((i) < 4 ? (h0) : (i) < 8 ? (h1) : (i) < 12 ? (h2) : (h3), (i))

__device__ __forceinline__ float4 mul4(float s, float4 w) {
    float4 r;
    r.x = s * w.x; r.y = s * w.y; r.z = s * w.z; r.w = s * w.w;
    return r;
}
__device__ __forceinline__ float4 fma4(float s, float4 w, float4 a) {
    a.x = fmaf(s, w.x, a.x); a.y = fmaf(s, w.y, a.y);
    a.z = fmaf(s, w.z, a.z); a.w = fmaf(s, w.w, a.w);
    return a;
}
__device__ __forceinline__ float elu_f(float v) {
    return v > 0.0f ? v : (__expf(v) - 1.0f);
}
__device__ __forceinline__ float4 elu4(float4 v) {
    float4 r;
    r.x = elu_f(v.x); r.y = elu_f(v.y); r.z = elu_f(v.z); r.w = elu_f(v.w);
    return r;
}
__device__ __forceinline__ float dot4(float4 a, float4 b) {
    return fmaf(a.x, b.x, fmaf(a.y, b.y, fmaf(a.z, b.z, a.w * b.w)));
}
__device__ __forceinline__ float4 zero4() {
    float4 r; r.x = 0.f; r.y = 0.f; r.z = 0.f; r.w = 0.f; return r;
}

// Full 16->16 layer, 2 samples. wbase = uniform global pointer to the 16x16
// block's row 0 (row stride 1024 floats). Loads are wave-uniform 64B rows ->
// SMEM s_load; accumulation order identical to R5/R6 (absmax-stable).
#define LAYER16G(wbase)                                                     \
    {                                                                       \
        float4 a0 = zero4(), a1 = zero4(), a2 = zero4(), a3 = zero4();      \
        float4 b0 = zero4(), b1 = zero4(), b2 = zero4(), b3 = zero4();      \
        _Pragma("unroll")                                                   \
        for (int i = 0; i < 16; ++i) {                                      \
            const float hai = GET16(ha0, ha1, ha2, ha3, i);                 \
            const float hbi = GET16(hb0, hb1, hb2, hb3, i);                 \
            const float4* wp = (const float4*)((wbase) + (size_t)i * 1024); \
            const float4 q0 = wp[0], q1 = wp[1], q2 = wp[2], q3 = wp[3];    \
            a0 = fma4(hai, q0, a0); a1 = fma4(hai, q1, a1);                 \
            a2 = fma4(hai, q2, a2); a3 = fma4(hai, q3, a3);                 \
            b0 = fma4(hbi, q0, b0); b1 = fma4(hbi, q1, b1);                 \
            b2 = fma4(hbi, q2, b2); b3 = fma4(hbi, q3, b3);                 \
        }                                                                   \
        ha0 = elu4(a0); ha1 = elu4(a1); ha2 = elu4(a2); ha3 = elu4(a3);     \
        hb0 = elu4(b0); hb1 = elu4(b1); hb2 = elu4(b2); hb3 = elu4(b3);     \
    }

// ---------------- fast path: transposed domain, SMEM weights --------------

// x (N,64) -> xt (64,N). 64x64 tiles via LDS (pad 65 -> conflict-free).
__global__ __launch_bounds__(256) void transpose_in(
    const float* __restrict__ x, float* __restrict__ xt, int nsamp)
{
    __shared__ float t[64][65];
    const int s0 = blockIdx.x * 64;
    const int c = threadIdx.x & 63;
    const int r0 = threadIdx.x >> 6;
    for (int i = r0; i < 64; i += 4)
        t[i][c] = x[(size_t)(s0 + i) * DTOT + c];
    __syncthreads();
    for (int d = r0; d < 64; d += 4)
        xt[(size_t)d * nsamp + s0 + c] = t[c][d];
}

// R6 structure, FGF=2 (4096 blocks for backfill) + next-feature x prefetch.
// No LDS, no barrier; weights via wave-uniform s_load.
__global__ __launch_bounds__(BLK) void gam_main_s(
    const float* __restrict__ xt, const float* __restrict__ W1,
    const float* __restrict__ W2, const float* __restrict__ W3,
    const float* __restrict__ W4, float* __restrict__ ot, int nsamp)
{
    const int tid = threadIdx.x;
    const int g = blockIdx.x & 31;       // feature group (32 groups of 2)
    const int chunk = blockIdx.x >> 5;   // sample chunk (512 samples)
    const int d0 = g * FGF;

    const int s0 = chunk * (BLK * 2) + tid;
    const int s1 = s0 + BLK;
    if (s0 >= nsamp) return;

    // prefetch feature d0's x pair
    float xv0 = xt[(size_t)d0 * nsamp + s0];
    float xv1 = xt[(size_t)d0 * nsamp + s1];

#pragma unroll 1
    for (int dd = 0; dd < FGF; ++dd) {
        const int d = d0 + dd;
        const size_t rowb = (size_t)d * nsamp;

        // issue next feature's x loads NOW; consumed next iteration
        const int dn = (dd + 1 < FGF) ? d + 1 : d;   // clamp: in-bounds
        const float xn0 = xt[(size_t)dn * nsamp + s0];
        const float xn1 = xt[(size_t)dn * nsamp + s1];

        // uniform per-feature weight bases (SALU arithmetic -> s_load)
        const float* w1p = W1 + (size_t)d * 1024 + d * 16;
        const float* w2p = W2 + (size_t)d * 16 * 1024 + d * 16;
        const float* w3p = W3 + (size_t)d * 16 * 1024 + d * 16;

        // layer 1
        const float4* u = (const float4*)w1p;
        const float4 u0 = u[0], u1 = u[1], u2 = u[2], u3 = u[3];
        float4 ha0 = elu4(mul4(xv0, u0)), ha1 = elu4(mul4(xv0, u1));
        float4 ha2 = elu4(mul4(xv0, u2)), ha3 = elu4(mul4(xv0, u3));
        float4 hb0 = elu4(mul4(xv1, u0)), hb1 = elu4(mul4(xv1, u1));
        float4 hb2 = elu4(mul4(xv1, u2)), hb3 = elu4(mul4(xv1, u3));

        // layers 2,3
        LAYER16G(w2p);
        LAYER16G(w3p);

        // layer 4: W4 column (stride 64) -> 16 uniform scalar loads
        float oa0 = 0.f, oa1 = 0.f, ob0 = 0.f, ob1 = 0.f;
#pragma unroll
        for (int i = 0; i < 16; i += 2) {
            const float wa = W4[(size_t)(d * 16 + i) * 64 + d];
            const float wb = W4[(size_t)(d * 16 + i + 1) * 64 + d];
            oa0 = fmaf(GET16(ha0, ha1, ha2, ha3, i), wa, oa0);
            ob0 = fmaf(GET16(hb0, hb1, hb2, hb3, i), wa, ob0);
            oa1 = fmaf(GET16(ha0, ha1, ha2, ha3, i + 1), wb, oa1);
            ob1 = fmaf(GET16(hb0, hb1, hb2, hb3, i + 1), wb, ob1);
        }
        ot[rowb + s0] = oa0 + oa1;                  // lane-contiguous
        ot[rowb + s1] = ob0 + ob1;

        xv0 = xn0;
        xv1 = xn1;
    }
}

// ot (64,N) -> out (N,64) AND pred[s] = bp + sum_d ot[d][s]*Wp[d], fused.
__global__ __launch_bounds__(256) void finish(
    const float* __restrict__ ot, const float* __restrict__ Wp,
    const float* __restrict__ bp, float* __restrict__ out,
    float* __restrict__ pred, int nsamp)
{
    __shared__ float t[64][65];
    __shared__ float wps[64];
    const int s0 = blockIdx.x * 64;
    const int c = threadIdx.x & 63;
    const int r0 = threadIdx.x >> 6;
    if (threadIdx.x < 64) wps[threadIdx.x] = Wp[threadIdx.x];
    for (int d = r0; d < 64; d += 4)
        t[d][c] = ot[(size_t)d * nsamp + s0 + c];
    __syncthreads();
    for (int i = r0; i < 64; i += 4)
        out[(size_t)(s0 + i) * DTOT + c] = t[c][i];   // full 256B lines
    if (r0 == 0) {
        float p = bp[0];
#pragma unroll
        for (int d = 0; d < 64; ++d)
            p = fmaf(t[d][c], wps[d], p);   // banks (d+c)%32: conflict-free
        pred[s0 + c] = p;
    }
}

// ---------------- fallback (ws too small; LDS-staged, strided I/O) --------

__device__ __forceinline__ void stage_weights(
    int tid, int d0,
    const float* __restrict__ W1, const float* __restrict__ W2,
    const float* __restrict__ W3, const float* __restrict__ W4,
    float (*w1s)[16], float (*w2s)[16][16], float (*w3s)[16][16], float (*w4s)[16])
{
    if (tid < 128) {
        int dd = tid >> 4, j = tid & 15;
        int d = d0 + dd;
        w1s[dd][j] = W1[d * 1024 + d * 16 + j];
    } else {
        int t = tid - 128;
        int dd = t >> 4, i = t & 15;
        int d = d0 + dd;
        w4s[dd][i] = W4[(d * 16 + i) * 64 + d];
    }
    for (int idx = tid; idx < FG * 256; idx += BLK) {
        int dd = idx >> 8, r = idx & 255;
        int i = r >> 4, j = r & 15;
        int d = d0 + dd;
        size_t base = (size_t)(d * 16 + i) * 1024 + d * 16 + j;
        w2s[dd][i][j] = W2[base];
        w3s[dd][i][j] = W3[base];
    }
}

#define LAYER16L(ws)                                                       \
    {                                                                      \
        float4 a0 = zero4(), a1 = zero4(), a2 = zero4(), a3 = zero4();     \
        float4 b0 = zero4(), b1 = zero4(), b2 = zero4(), b3 = zero4();     \
        _Pragma("unroll")                                                  \
        for (int i = 0; i < 16; ++i) {                                     \
            const float hai = GET16(ha0, ha1, ha2, ha3, i);                \
            const float hbi = GET16(hb0, hb1, hb2, hb3, i);                \
            const float4* wp = (const float4*)((ws) + i * 16);             \
            const float4 q0 = wp[0], q1 = wp[1], q2 = wp[2], q3 = wp[3];   \
            a0 = fma4(hai, q0, a0); a1 = fma4(hai, q1, a1);                \
            a2 = fma4(hai, q2, a2); a3 = fma4(hai, q3, a3);                \
            b0 = fma4(hbi, q0, b0); b1 = fma4(hbi, q1, b1);                \
            b2 = fma4(hbi, q2, b2); b3 = fma4(hbi, q3, b3);                \
        }                                                                  \
        ha0 = elu4(a0); ha1 = elu4(a1); ha2 = elu4(a2); ha3 = elu4(a3);    \
        hb0 = elu4(b0); hb1 = elu4(b1); hb2 = elu4(b2); hb3 = elu4(b3);    \
    }

__global__ __launch_bounds__(BLK, 4) void gam_main_direct(
    const float* __restrict__ x, const float* __restrict__ W1,
    const float* __restrict__ W2, const float* __restrict__ W3,
    const float* __restrict__ W4, float* __restrict__ out, int nsamp)
{
    __shared__ float w1s[FG][16];
    __shared__ float w2s[FG][16][16];
    __shared__ float w3s[FG][16][16];
    __shared__ float w4s[FG][16];

    const int tid = threadIdx.x;
    const int g = blockIdx.x & 7;
    const int chunk = blockIdx.x >> 3;
    const int d0 = g * FG;

    stage_weights(tid, d0, W1, W2, W3, W4, w1s, w2s, w3s, w4s);
    __syncthreads();

    const int s0 = chunk * (BLK * 2) + tid;
    const int s1 = s0 + BLK;
    if (s0 >= nsamp) return;

    for (int dd = 0; dd < FG; ++dd) {
        const int d = d0 + dd;
        const float xv0 = x[(size_t)s0 * DTOT + d];
        const float xv1 = x[(size_t)s1 * DTOT + d];

        const float4* w1p = (const float4*)&w1s[dd][0];
        const float4 u0 = w1p[0], u1 = w1p[1], u2 = w1p[2], u3 = w1p[3];
        float4 ha0 = elu4(mul4(xv0, u0)), ha1 = elu4(mul4(xv0, u1));
        float4 ha2 = elu4(mul4(xv0, u2)), ha3 = elu4(mul4(xv0, u3));
        float4 hb0 = elu4(mul4(xv1, u0)), hb1 = elu4(mul4(xv1, u1));
        float4 hb2 = elu4(mul4(xv1, u2)), hb3 = elu4(mul4(xv1, u3));

        LAYER16L(&w2s[dd][0][0]);
        LAYER16L(&w3s[dd][0][0]);

        const float4* w4p = (const float4*)&w4s[dd][0];
        const float4 q0 = w4p[0], q1 = w4p[1], q2 = w4p[2], q3 = w4p[3];
        out[(size_t)s0 * DTOT + d] = (dot4(ha0, q0) + dot4(ha1, q1)) +
                                     (dot4(ha2, q2) + dot4(ha3, q3));
        out[(size_t)s1 * DTOT + d] = (dot4(hb0, q0) + dot4(hb1, q1)) +
                                     (dot4(hb2, q2) + dot4(hb3, q3));
    }
}

__global__ __launch_bounds__(BLK) void gam_pred_direct(
    const float* __restrict__ out, const float* __restrict__ Wp,
    const float* __restrict__ bp, float* __restrict__ pred, int nsamp)
{
    int gid = blockIdx.x * BLK + threadIdx.x;
    int wave = gid >> 6, lane = gid & 63;
    int sub = lane >> 4, li = lane & 15;
    int s = wave * 4 + sub;
    if (s >= nsamp) return;
    float4 wv = ((const float4*)Wp)[li];
    float4 v = ((const float4*)(out + (size_t)s * DTOT))[li];
    float p = v.x * wv.x + v.y * wv.y + v.z * wv.z + v.w * wv.w;
    p += __shfl_xor(p, 1);
    p += __shfl_xor(p, 2);
    p += __shfl_xor(p, 4);
    p += __shfl_xor(p, 8);
    if (li == 0) pred[s] = p + bp[0];
}

extern "C" void kernel_launch(void* const* d_in, const int* in_sizes, int n_in,
                              void* d_out, int out_size, void* d_ws, size_t ws_size,
                              hipStream_t stream) {
    const float* x  = (const float*)d_in[0];
    const float* W1 = (const float*)d_in[1];
    const float* W2 = (const float*)d_in[2];
    const float* W3 = (const float*)d_in[3];
    const float* W4 = (const float*)d_in[4];
    const float* Wp = (const float*)d_in[5];
    const float* bp = (const float*)d_in[6];

    const int nsamp = in_sizes[0] / DTOT;   // 65536
    float* pred = (float*)d_out;            // (N,1) first
    float* outm = pred + nsamp;             // (N,64) second

    const size_t need = (size_t)2 * nsamp * DTOT * sizeof(float);
    if (ws_size >= need && (nsamp % (BLK * 2)) == 0 && (nsamp % 64) == 0) {
        float* xt = (float*)d_ws;
        float* ot = xt + (size_t)nsamp * DTOT;
        transpose_in<<<dim3(nsamp / 64), dim3(256), 0, stream>>>(x, xt, nsamp);
        // nsamp/512 chunks x 32 groups (FGF=2) = 4096 blocks
        gam_main_s<<<dim3((nsamp / (BLK * 2)) * 32), dim3(BLK), 0, stream>>>(
            xt, W1, W2, W3, W4, ot, nsamp);
        finish<<<dim3(nsamp / 64), dim3(256), 0, stream>>>(
            ot, Wp, bp, outm, pred, nsamp);
    } else {
        int chunks = nsamp / (BLK * 2);
        gam_main_direct<<<dim3(chunks * 8), dim3(BLK), 0, stream>>>(
            x, W1, W2, W3, W4, outm, nsamp);
        int nthreads = (nsamp / 4) * 64;
        gam_pred_direct<<<dim3((nthreads + BLK - 1) / BLK), dim3(BLK), 0, stream>>>(
            outm, Wp, bp, pred, nsamp);
    }
}

// Round 12
// 85.791 us; speedup vs baseline: 1.2108x; 1.0365x over previous
//
#include <hip/hip_runtime.h>

// GAM forward: 64 per-feature MLPs 1->16->16->16->1 (ELU), pred = out@Wp+bp.
// R1: row-major lane=sample access -> 250x RMW blowup. Fixed: transposed ws.
// R2/R5: pointer-cast local arrays -> scratch spill. Fixed: reg-friendly state.
// R6: LDS eliminated via wave-uniform s_load weights -> 82us, VALUBusy 79%.
// R7/R9: v_pk_fma_f32 dead by spec (157.3TF = unpacked rate on CDNA4);
//   builtin path scalarized + packing movs = pure loss. Axis closed.
// R11: FGF=2 backfill -> 79.9us, occ 52.8, busy 66.5us (floor ~45 + ~20us
//   suspected SGPR->VGPR weight staging, unfixable without disasm).
// R12: FGF=1 -> 8192 blocks (4x residency round): drain tail halves again.
//   If occ rises but dur >=78: declare structural floor.

#define BLK 256
#define FG 8        // features per block (fallback path)
#define DTOT 64

__device__ __forceinline__ float getc(float4 v, int i) {
    switch (i & 3) {
        case 0: return v.x;
        case 1: return v.y;
        case 2: return v.z;
        default: return v.w;
    }
}
// compile-time-folded 16-way select (i is a constant under #pragma unroll)
#define GET16(h0, h1, h2, h3, i) \
    getc((i) < 4 ? (h0) : (i) < 8 ? (h1) : (i) < 12 ? (h2) : (h3), (i))

__device__ __forceinline__ float4 mul4(float s, float4 w) {
    float4 r;
    r.x = s * w.x; r.y = s * w.y; r.z = s * w.z; r.w = s * w.w;
    return r;
}
__device__ __forceinline__ float4 fma4(float s, float4 w, float4 a) {
    a.x = fmaf(s, w.x, a.x); a.y = fmaf(s, w.y, a.y);
    a.z = fmaf(s, w.z, a.z); a.w = fmaf(s, w.w, a.w);
    return a;
}
__device__ __forceinline__ float elu_f(float v) {
    return v > 0.0f ? v : (__expf(v) - 1.0f);
}
__device__ __forceinline__ float4 elu4(float4 v) {
    float4 r;
    r.x = elu_f(v.x); r.y = elu_f(v.y); r.z = elu_f(v.z); r.w = elu_f(v.w);
    return r;
}
__device__ __forceinline__ float dot4(float4 a, float4 b) {
    return fmaf(a.x, b.x, fmaf(a.y, b.y, fmaf(a.z, b.z, a.w * b.w)));
}
__device__ __forceinline__ float4 zero4() {
    float4 r; r.x = 0.f; r.y = 0.f; r.z = 0.f; r.w = 0.f; return r;
}

// Full 16->16 layer, 2 samples. wbase = uniform global pointer to the 16x16
// block's row 0 (row stride 1024 floats). Loads are wave-uniform 64B rows ->
// SMEM s_load; accumulation order identical to R5/R6 (absmax-stable).
#define LAYER16G(wbase)                                                     \
    {                                                                       \
        float4 a0 = zero4(), a1 = zero4(), a2 = zero4(), a3 = zero4();      \
        float4 b0 = zero4(), b1 = zero4(), b2 = zero4(), b3 = zero4();      \
        _Pragma("unroll")                                                   \
        for (int i = 0; i < 16; ++i) {                                      \
            const float hai = GET16(ha0, ha1, ha2, ha3, i);                 \
            const float hbi = GET16(hb0, hb1, hb2, hb3, i);                 \
            const float4* wp = (const float4*)((wbase) + (size_t)i * 1024); \
            const float4 q0 = wp[0], q1 = wp[1], q2 = wp[2], q3 = wp[3];    \
            a0 = fma4(hai, q0, a0); a1 = fma4(hai, q1, a1);                 \
            a2 = fma4(hai, q2, a2); a3 = fma4(hai, q3, a3);                 \
            b0 = fma4(hbi, q0, b0); b1 = fma4(hbi, q1, b1);                 \
            b2 = fma4(hbi, q2, b2); b3 = fma4(hbi, q3, b3);                 \
        }                                                                   \
        ha0 = elu4(a0); ha1 = elu4(a1); ha2 = elu4(a2); ha3 = elu4(a3);     \
        hb0 = elu4(b0); hb1 = elu4(b1); hb2 = elu4(b2); hb3 = elu4(b3);     \
    }

// ---------------- fast path: transposed domain, SMEM weights --------------

// x (N,64) -> xt (64,N). 64x64 tiles via LDS (pad 65 -> conflict-free).
__global__ __launch_bounds__(256) void transpose_in(
    const float* __restrict__ x, float* __restrict__ xt, int nsamp)
{
    __shared__ float t[64][65];
    const int s0 = blockIdx.x * 64;
    const int c = threadIdx.x & 63;
    const int r0 = threadIdx.x >> 6;
    for (int i = r0; i < 64; i += 4)
        t[i][c] = x[(size_t)(s0 + i) * DTOT + c];
    __syncthreads();
    for (int d = r0; d < 64; d += 4)
        xt[(size_t)d * nsamp + s0 + c] = t[c][d];
}

// FGF=1: one feature per block, 8192 blocks (4x residency round).
// No LDS, no barrier; weights via wave-uniform s_load.
__global__ __launch_bounds__(BLK) void gam_main_s(
    const float* __restrict__ xt, const float* __restrict__ W1,
    const float* __restrict__ W2, const float* __restrict__ W3,
    const float* __restrict__ W4, float* __restrict__ ot, int nsamp)
{
    const int tid = threadIdx.x;
    const int d = blockIdx.x & 63;       // feature (64 groups of 1)
    const int chunk = blockIdx.x >> 6;   // sample chunk (512 samples)

    const int s0 = chunk * (BLK * 2) + tid;
    const int s1 = s0 + BLK;
    if (s0 >= nsamp) return;

    const size_t rowb = (size_t)d * nsamp;
    const float xv0 = xt[rowb + s0];                // lane-contiguous
    const float xv1 = xt[rowb + s1];

    // uniform per-feature weight bases (SALU arithmetic -> s_load)
    const float* w1p = W1 + (size_t)d * 1024 + d * 16;
    const float* w2p = W2 + (size_t)d * 16 * 1024 + d * 16;
    const float* w3p = W3 + (size_t)d * 16 * 1024 + d * 16;

    // layer 1
    const float4* u = (const float4*)w1p;
    const float4 u0 = u[0], u1 = u[1], u2 = u[2], u3 = u[3];
    float4 ha0 = elu4(mul4(xv0, u0)), ha1 = elu4(mul4(xv0, u1));
    float4 ha2 = elu4(mul4(xv0, u2)), ha3 = elu4(mul4(xv0, u3));
    float4 hb0 = elu4(mul4(xv1, u0)), hb1 = elu4(mul4(xv1, u1));
    float4 hb2 = elu4(mul4(xv1, u2)), hb3 = elu4(mul4(xv1, u3));

    // layers 2,3
    LAYER16G(w2p);
    LAYER16G(w3p);

    // layer 4: W4 column (stride 64) -> 16 uniform scalar loads
    float oa0 = 0.f, oa1 = 0.f, ob0 = 0.f, ob1 = 0.f;
#pragma unroll
    for (int i = 0; i < 16; i += 2) {
        const float wa = W4[(size_t)(d * 16 + i) * 64 + d];
        const float wb = W4[(size_t)(d * 16 + i + 1) * 64 + d];
        oa0 = fmaf(GET16(ha0, ha1, ha2, ha3, i), wa, oa0);
        ob0 = fmaf(GET16(hb0, hb1, hb2, hb3, i), wa, ob0);
        oa1 = fmaf(GET16(ha0, ha1, ha2, ha3, i + 1), wb, oa1);
        ob1 = fmaf(GET16(hb0, hb1, hb2, hb3, i + 1), wb, ob1);
    }
    ot[rowb + s0] = oa0 + oa1;                      // lane-contiguous
    ot[rowb + s1] = ob0 + ob1;
}

// ot (64,N) -> out (N,64) AND pred[s] = bp + sum_d ot[d][s]*Wp[d], fused.
__global__ __launch_bounds__(256) void finish(
    const float* __restrict__ ot, const float* __restrict__ Wp,
    const float* __restrict__ bp, float* __restrict__ out,
    float* __restrict__ pred, int nsamp)
{
    __shared__ float t[64][65];
    __shared__ float wps[64];
    const int s0 = blockIdx.x * 64;
    const int c = threadIdx.x & 63;
    const int r0 = threadIdx.x >> 6;
    if (threadIdx.x < 64) wps[threadIdx.x] = Wp[threadIdx.x];
    for (int d = r0; d < 64; d += 4)
        t[d][c] = ot[(size_t)d * nsamp + s0 + c];
    __syncthreads();
    for (int i = r0; i < 64; i += 4)
        out[(size_t)(s0 + i) * DTOT + c] = t[c][i];   // full 256B lines
    if (r0 == 0) {
        float p = bp[0];
#pragma unroll
        for (int d = 0; d < 64; ++d)
            p = fmaf(t[d][c], wps[d], p);   // banks (d+c)%32: conflict-free
        pred[s0 + c] = p;
    }
}

// ---------------- fallback (ws too small; LDS-staged, strided I/O) --------

__device__ __forceinline__ void stage_weights(
    int tid, int d0,
    const float* __restrict__ W1, const float* __restrict__ W2,
    const float* __restrict__ W3, const float* __restrict__ W4,
    float (*w1s)[16], float (*w2s)[16][16], float (*w3s)[16][16], float (*w4s)[16])
{
    if (tid < 128) {
        int dd = tid >> 4, j = tid & 15;
        int d = d0 + dd;
        w1s[dd][j] = W1[d * 1024 + d * 16 + j];
    } else {
        int t = tid - 128;
        int dd = t >> 4, i = t & 15;
        int d = d0 + dd;
        w4s[dd][i] = W4[(d * 16 + i) * 64 + d];
    }
    for (int idx = tid; idx < FG * 256; idx += BLK) {
        int dd = idx >> 8, r = idx & 255;
        int i = r >> 4, j = r & 15;
        int d = d0 + dd;
        size_t base = (size_t)(d * 16 + i) * 1024 + d * 16 + j;
        w2s[dd][i][j] = W2[base];
        w3s[dd][i][j] = W3[base];
    }
}

#define LAYER16L(ws)                                                       \
    {                                                                      \
        float4 a0 = zero4(), a1 = zero4(), a2 = zero4(), a3 = zero4();     \
        float4 b0 = zero4(), b1 = zero4(), b2 = zero4(), b3 = zero4();     \
        _Pragma("unroll")                                                  \
        for (int i = 0; i < 16; ++i) {                                     \
            const float hai = GET16(ha0, ha1, ha2, ha3, i);                \
            const float hbi = GET16(hb0, hb1, hb2, hb3, i);                \
            const float4* wp = (const float4*)((ws) + i * 16);             \
            const float4 q0 = wp[0], q1 = wp[1], q2 = wp[2], q3 = wp[3];   \
            a0 = fma4(hai, q0, a0); a1 = fma4(hai, q1, a1);                \
            a2 = fma4(hai, q2, a2); a3 = fma4(hai, q3, a3);                \
            b0 = fma4(hbi, q0, b0); b1 = fma4(hbi, q1, b1);                \
            b2 = fma4(hbi, q2, b2); b3 = fma4(hbi, q3, b3);                \
        }                                                                  \
        ha0 = elu4(a0); ha1 = elu4(a1); ha2 = elu4(a2); ha3 = elu4(a3);    \
        hb0 = elu4(b0); hb1 = elu4(b1); hb2 = elu4(b2); hb3 = elu4(b3);    \
    }

__global__ __launch_bounds__(BLK, 4) void gam_main_direct(
    const float* __restrict__ x, const float* __restrict__ W1,
    const float* __restrict__ W2, const float* __restrict__ W3,
    const float* __restrict__ W4, float* __restrict__ out, int nsamp)
{
    __shared__ float w1s[FG][16];
    __shared__ float w2s[FG][16][16];
    __shared__ float w3s[FG][16][16];
    __shared__ float w4s[FG][16];

    const int tid = threadIdx.x;
    const int g = blockIdx.x & 7;
    const int chunk = blockIdx.x >> 3;
    const int d0 = g * FG;

    stage_weights(tid, d0, W1, W2, W3, W4, w1s, w2s, w3s, w4s);
    __syncthreads();

    const int s0 = chunk * (BLK * 2) + tid;
    const int s1 = s0 + BLK;
    if (s0 >= nsamp) return;

    for (int dd = 0; dd < FG; ++dd) {
        const int d = d0 + dd;
        const float xv0 = x[(size_t)s0 * DTOT + d];
        const float xv1 = x[(size_t)s1 * DTOT + d];

        const float4* w1p = (const float4*)&w1s[dd][0];
        const float4 u0 = w1p[0], u1 = w1p[1], u2 = w1p[2], u3 = w1p[3];
        float4 ha0 = elu4(mul4(xv0, u0)), ha1 = elu4(mul4(xv0, u1));
        float4 ha2 = elu4(mul4(xv0, u2)), ha3 = elu4(mul4(xv0, u3));
        float4 hb0 = elu4(mul4(xv1, u0)), hb1 = elu4(mul4(xv1, u1));
        float4 hb2 = elu4(mul4(xv1, u2)), hb3 = elu4(mul4(xv1, u3));

        LAYER16L(&w2s[dd][0][0]);
        LAYER16L(&w3s[dd][0][0]);

        const float4* w4p = (const float4*)&w4s[dd][0];
        const float4 q0 = w4p[0], q1 = w4p[1], q2 = w4p[2], q3 = w4p[3];
        out[(size_t)s0 * DTOT + d] = (dot4(ha0, q0) + dot4(ha1, q1)) +
                                     (dot4(ha2, q2) + dot4(ha3, q3));
        out[(size_t)s1 * DTOT + d] = (dot4(hb0, q0) + dot4(hb1, q1)) +
                                     (dot4(hb2, q2) + dot4(hb3, q3));
    }
}

__global__ __launch_bounds__(BLK) void gam_pred_direct(
    const float* __restrict__ out, const float* __restrict__ Wp,
    const float* __restrict__ bp, float* __restrict__ pred, int nsamp)
{
    int gid = blockIdx.x * BLK + threadIdx.x;
    int wave = gid >> 6, lane = gid & 63;
    int sub = lane >> 4, li = lane & 15;
    int s = wave * 4 + sub;
    if (s >= nsamp) return;
    float4 wv = ((const float4*)Wp)[li];
    float4 v = ((const float4*)(out + (size_t)s * DTOT))[li];
    float p = v.x * wv.x + v.y * wv.y + v.z * wv.z + v.w * wv.w;
    p += __shfl_xor(p, 1);
    p += __shfl_xor(p, 2);
    p += __shfl_xor(p, 4);
    p += __shfl_xor(p, 8);
    if (li == 0) pred[s] = p + bp[0];
}

extern "C" void kernel_launch(void* const* d_in, const int* in_sizes, int n_in,
                              void* d_out, int out_size, void* d_ws, size_t ws_size,
                              hipStream_t stream) {
    const float* x  = (const float*)d_in[0];
    const float* W1 = (const float*)d_in[1];
    const float* W2 = (const float*)d_in[2];
    const float* W3 = (const float*)d_in[3];
    const float* W4 = (const float*)d_in[4];
    const float* Wp = (const float*)d_in[5];
    const float* bp = (const float*)d_in[6];

    const int nsamp = in_sizes[0] / DTOT;   // 65536
    float* pred = (float*)d_out;            // (N,1) first
    float* outm = pred + nsamp;             // (N,64) second

    const size_t need = (size_t)2 * nsamp * DTOT * sizeof(float);
    if (ws_size >= need && (nsamp % (BLK * 2)) == 0 && (nsamp % 64) == 0) {
        float* xt = (float*)d_ws;
        float* ot = xt + (size_t)nsamp * DTOT;
        transpose_in<<<dim3(nsamp / 64), dim3(256), 0, stream>>>(x, xt, nsamp);
        // nsamp/512 chunks x 64 features (FGF=1) = 8192 blocks
        gam_main_s<<<dim3((nsamp / (BLK * 2)) * 64), dim3(BLK), 0, stream>>>(
            xt, W1, W2, W3, W4, ot, nsamp);
        finish<<<dim3(nsamp / 64), dim3(256), 0, stream>>>(
            ot, Wp, bp, outm, pred, nsamp);
    } else {
        int chunks = nsamp / (BLK * 2);
        gam_main_direct<<<dim3(chunks * 8), dim3(BLK), 0, stream>>>(
            x, W1, W2, W3, W4, outm, nsamp);
        int nthreads = (nsamp / 4) * 64;
        gam_pred_direct<<<dim3((nthreads + BLK - 1) / BLK), dim3(BLK), 0, stream>>>(
            outm, Wp, bp, pred, nsamp);
    }
}

// Round 13
// 85.656 us; speedup vs baseline: 1.2127x; 1.0016x over previous
//
#include <hip/hip_runtime.h>

// GAM forward: 64 per-feature MLPs 1->16->16->16->1 (ELU), pred = out@Wp+bp.
// R1: row-major lane=sample access -> 250x RMW blowup. Fixed: transposed ws.
// R2/R5: pointer-cast local arrays -> scratch spill. Fixed: reg-friendly state.
// R6: LDS eliminated via wave-uniform s_load weights -> 82us, VALUBusy 79%.
// R7/R9: v_pk_fma_f32 dead by spec (157.3TF = unpacked rate); axis closed.
// R11/R12: grain count 2048->4096->8192 blocks: 82->79.9->76.3us, occ 46->55,
//   busy constant ~64us (floor ~51: FMA 43 + exp premium 8; gap = SGPR
//   staging). Side kernels at HBM floor (~10us/67MB).
// R13: BLK=128 (2-wave blocks, 16384 grains): workgroup slots (~16/CU) can
//   hold 32 waves = full cap; finest backfill. If dur>=75: structural floor.

#define BLK 256      // block size for transpose/finish/fallback
#define BLKM 128     // block size for main kernel (2 waves)
#define FG 8         // features per block (fallback path)
#define DTOT 64

__device__ __forceinline__ float getc(float4 v, int i) {
    switch (i & 3) {
        case 0: return v.x;
        case 1: return v.y;
        case 2: return v.z;
        default: return v.w;
    }
}
// compile-time-folded 16-way select (i is a constant under #pragma unroll)
#define GET16(h0, h1, h2, h3, i) \
    getc((i) < 4 ? (h0) : (i) < 8 ? (h1) : (i) < 12 ? (h2) : (h3), (i))

__device__ __forceinline__ float4 mul4(float s, float4 w) {
    float4 r;
    r.x = s * w.x; r.y = s * w.y; r.z = s * w.z; r.w = s * w.w;
    return r;
}
__device__ __forceinline__ float4 fma4(float s, float4 w, float4 a) {
    a.x = fmaf(s, w.x, a.x); a.y = fmaf(s, w.y, a.y);
    a.z = fmaf(s, w.z, a.z); a.w = fmaf(s, w.w, a.w);
    return a;
}
__device__ __forceinline__ float elu_f(float v) {
    return v > 0.0f ? v : (__expf(v) - 1.0f);
}
__device__ __forceinline__ float4 elu4(float4 v) {
    float4 r;
    r.x = elu_f(v.x); r.y = elu_f(v.y); r.z = elu_f(v.z); r.w = elu_f(v.w);
    return r;
}
__device__ __forceinline__ float dot4(float4 a, float4 b) {
    return fmaf(a.x, b.x, fmaf(a.y, b.y, fmaf(a.z, b.z, a.w * b.w)));
}
__device__ __forceinline__ float4 zero4() {
    float4 r; r.x = 0.f; r.y = 0.f; r.z = 0.f; r.w = 0.f; return r;
}

// Full 16->16 layer, 2 samples. wbase = uniform global pointer to the 16x16
// block's row 0 (row stride 1024 floats). Loads are wave-uniform 64B rows ->
// SMEM s_load; accumulation order identical to R5/R6 (absmax-stable).
#define LAYER16G(wbase)                                                     \
    {                                                                       \
        float4 a0 = zero4(), a1 = zero4(), a2 = zero4(), a3 = zero4();      \
        float4 b0 = zero4(), b1 = zero4(), b2 = zero4(), b3 = zero4();      \
        _Pragma("unroll")                                                   \
        for (int i = 0; i < 16; ++i) {                                      \
            const float hai = GET16(ha0, ha1, ha2, ha3, i);                 \
            const float hbi = GET16(hb0, hb1, hb2, hb3, i);                 \
            const float4* wp = (const float4*)((wbase) + (size_t)i * 1024); \
            const float4 q0 = wp[0], q1 = wp[1], q2 = wp[2], q3 = wp[3];    \
            a0 = fma4(hai, q0, a0); a1 = fma4(hai, q1, a1);                 \
            a2 = fma4(hai, q2, a2); a3 = fma4(hai, q3, a3);                 \
            b0 = fma4(hbi, q0, b0); b1 = fma4(hbi, q1, b1);                 \
            b2 = fma4(hbi, q2, b2); b3 = fma4(hbi, q3, b3);                 \
        }                                                                   \
        ha0 = elu4(a0); ha1 = elu4(a1); ha2 = elu4(a2); ha3 = elu4(a3);     \
        hb0 = elu4(b0); hb1 = elu4(b1); hb2 = elu4(b2); hb3 = elu4(b3);     \
    }

// ---------------- fast path: transposed domain, SMEM weights --------------

// x (N,64) -> xt (64,N). 64x64 tiles via LDS (pad 65 -> conflict-free).
__global__ __launch_bounds__(256) void transpose_in(
    const float* __restrict__ x, float* __restrict__ xt, int nsamp)
{
    __shared__ float t[64][65];
    const int s0 = blockIdx.x * 64;
    const int c = threadIdx.x & 63;
    const int r0 = threadIdx.x >> 6;
    for (int i = r0; i < 64; i += 4)
        t[i][c] = x[(size_t)(s0 + i) * DTOT + c];
    __syncthreads();
    for (int d = r0; d < 64; d += 4)
        xt[(size_t)d * nsamp + s0 + c] = t[c][d];
}

// FGF=1, BLKM=128: one feature, 256 samples (2/thread), 16384 blocks.
// No LDS, no barrier; weights via wave-uniform s_load.
__global__ __launch_bounds__(BLKM) void gam_main_s(
    const float* __restrict__ xt, const float* __restrict__ W1,
    const float* __restrict__ W2, const float* __restrict__ W3,
    const float* __restrict__ W4, float* __restrict__ ot, int nsamp)
{
    const int tid = threadIdx.x;
    const int d = blockIdx.x & 63;       // feature
    const int chunk = blockIdx.x >> 6;   // sample chunk (256 samples)

    const int s0 = chunk * (BLKM * 2) + tid;
    const int s1 = s0 + BLKM;
    if (s0 >= nsamp) return;

    const size_t rowb = (size_t)d * nsamp;
    const float xv0 = xt[rowb + s0];                // lane-contiguous
    const float xv1 = xt[rowb + s1];

    // uniform per-feature weight bases (SALU arithmetic -> s_load)
    const float* w1p = W1 + (size_t)d * 1024 + d * 16;
    const float* w2p = W2 + (size_t)d * 16 * 1024 + d * 16;
    const float* w3p = W3 + (size_t)d * 16 * 1024 + d * 16;

    // layer 1
    const float4* u = (const float4*)w1p;
    const float4 u0 = u[0], u1 = u[1], u2 = u[2], u3 = u[3];
    float4 ha0 = elu4(mul4(xv0, u0)), ha1 = elu4(mul4(xv0, u1));
    float4 ha2 = elu4(mul4(xv0, u2)), ha3 = elu4(mul4(xv0, u3));
    float4 hb0 = elu4(mul4(xv1, u0)), hb1 = elu4(mul4(xv1, u1));
    float4 hb2 = elu4(mul4(xv1, u2)), hb3 = elu4(mul4(xv1, u3));

    // layers 2,3
    LAYER16G(w2p);
    LAYER16G(w3p);

    // layer 4: W4 column (stride 64) -> 16 uniform scalar loads
    float oa0 = 0.f, oa1 = 0.f, ob0 = 0.f, ob1 = 0.f;
#pragma unroll
    for (int i = 0; i < 16; i += 2) {
        const float wa = W4[(size_t)(d * 16 + i) * 64 + d];
        const float wb = W4[(size_t)(d * 16 + i + 1) * 64 + d];
        oa0 = fmaf(GET16(ha0, ha1, ha2, ha3, i), wa, oa0);
        ob0 = fmaf(GET16(hb0, hb1, hb2, hb3, i), wa, ob0);
        oa1 = fmaf(GET16(ha0, ha1, ha2, ha3, i + 1), wb, oa1);
        ob1 = fmaf(GET16(hb0, hb1, hb2, hb3, i + 1), wb, ob1);
    }
    ot[rowb + s0] = oa0 + oa1;                      // lane-contiguous
    ot[rowb + s1] = ob0 + ob1;
}

// ot (64,N) -> out (N,64) AND pred[s] = bp + sum_d ot[d][s]*Wp[d], fused.
__global__ __launch_bounds__(256) void finish(
    const float* __restrict__ ot, const float* __restrict__ Wp,
    const float* __restrict__ bp, float* __restrict__ out,
    float* __restrict__ pred, int nsamp)
{
    __shared__ float t[64][65];
    __shared__ float wps[64];
    const int s0 = blockIdx.x * 64;
    const int c = threadIdx.x & 63;
    const int r0 = threadIdx.x >> 6;
    if (threadIdx.x < 64) wps[threadIdx.x] = Wp[threadIdx.x];
    for (int d = r0; d < 64; d += 4)
        t[d][c] = ot[(size_t)d * nsamp + s0 + c];
    __syncthreads();
    for (int i = r0; i < 64; i += 4)
        out[(size_t)(s0 + i) * DTOT + c] = t[c][i];   // full 256B lines
    if (r0 == 0) {
        float p = bp[0];
#pragma unroll
        for (int d = 0; d < 64; ++d)
            p = fmaf(t[d][c], wps[d], p);   // banks (d+c)%32: conflict-free
        pred[s0 + c] = p;
    }
}

// ---------------- fallback (ws too small; LDS-staged, strided I/O) --------

__device__ __forceinline__ void stage_weights(
    int tid, int d0,
    const float* __restrict__ W1, const float* __restrict__ W2,
    const float* __restrict__ W3, const float* __restrict__ W4,
    float (*w1s)[16], float (*w2s)[16][16], float (*w3s)[16][16], float (*w4s)[16])
{
    if (tid < 128) {
        int dd = tid >> 4, j = tid & 15;
        int d = d0 + dd;
        w1s[dd][j] = W1[d * 1024 + d * 16 + j];
    } else {
        int t = tid - 128;
        int dd = t >> 4, i = t & 15;
        int d = d0 + dd;
        w4s[dd][i] = W4[(d * 16 + i) * 64 + d];
    }
    for (int idx = tid; idx < FG * 256; idx += BLK) {
        int dd = idx >> 8, r = idx & 255;
        int i = r >> 4, j = r & 15;
        int d = d0 + dd;
        size_t base = (size_t)(d * 16 + i) * 1024 + d * 16 + j;
        w2s[dd][i][j] = W2[base];
        w3s[dd][i][j] = W3[base];
    }
}

#define LAYER16L(ws)                                                       \
    {                                                                      \
        float4 a0 = zero4(), a1 = zero4(), a2 = zero4(), a3 = zero4();     \
        float4 b0 = zero4(), b1 = zero4(), b2 = zero4(), b3 = zero4();     \
        _Pragma("unroll")                                                  \
        for (int i = 0; i < 16; ++i) {                                     \
            const float hai = GET16(ha0, ha1, ha2, ha3, i);                \
            const float hbi = GET16(hb0, hb1, hb2, hb3, i);                \
            const float4* wp = (const float4*)((ws) + i * 16);             \
            const float4 q0 = wp[0], q1 = wp[1], q2 = wp[2], q3 = wp[3];   \
            a0 = fma4(hai, q0, a0); a1 = fma4(hai, q1, a1);                \
            a2 = fma4(hai, q2, a2); a3 = fma4(hai, q3, a3);                \
            b0 = fma4(hbi, q0, b0); b1 = fma4(hbi, q1, b1);                \
            b2 = fma4(hbi, q2, b2); b3 = fma4(hbi, q3, b3);                \
        }                                                                  \
        ha0 = elu4(a0); ha1 = elu4(a1); ha2 = elu4(a2); ha3 = elu4(a3);    \
        hb0 = elu4(b0); hb1 = elu4(b1); hb2 = elu4(b2); hb3 = elu4(b3);    \
    }

__global__ __launch_bounds__(BLK, 4) void gam_main_direct(
    const float* __restrict__ x, const float* __restrict__ W1,
    const float* __restrict__ W2, const float* __restrict__ W3,
    const float* __restrict__ W4, float* __restrict__ out, int nsamp)
{
    __shared__ float w1s[FG][16];
    __shared__ float w2s[FG][16][16];
    __shared__ float w3s[FG][16][16];
    __shared__ float w4s[FG][16];

    const int tid = threadIdx.x;
    const int g = blockIdx.x & 7;
    const int chunk = blockIdx.x >> 3;
    const int d0 = g * FG;

    stage_weights(tid, d0, W1, W2, W3, W4, w1s, w2s, w3s, w4s);
    __syncthreads();

    const int s0 = chunk * (BLK * 2) + tid;
    const int s1 = s0 + BLK;
    if (s0 >= nsamp) return;

    for (int dd = 0; dd < FG; ++dd) {
        const int d = d0 + dd;
        const float xv0 = x[(size_t)s0 * DTOT + d];
        const float xv1 = x[(size_t)s1 * DTOT + d];

        const float4* w1p = (const float4*)&w1s[dd][0];
        const float4 u0 = w1p[0], u1 = w1p[1], u2 = w1p[2], u3 = w1p[3];
        float4 ha0 = elu4(mul4(xv0, u0)), ha1 = elu4(mul4(xv0, u1));
        float4 ha2 = elu4(mul4(xv0, u2)), ha3 = elu4(mul4(xv0, u3));
        float4 hb0 = elu4(mul4(xv1, u0)), hb1 = elu4(mul4(xv1, u1));
        float4 hb2 = elu4(mul4(xv1, u2)), hb3 = elu4(mul4(xv1, u3));

        LAYER16L(&w2s[dd][0][0]);
        LAYER16L(&w3s[dd][0][0]);

        const float4* w4p = (const float4*)&w4s[dd][0];
        const float4 q0 = w4p[0], q1 = w4p[1], q2 = w4p[2], q3 = w4p[3];
        out[(size_t)s0 * DTOT + d] = (dot4(ha0, q0) + dot4(ha1, q1)) +
                                     (dot4(ha2, q2) + dot4(ha3, q3));
        out[(size_t)s1 * DTOT + d] = (dot4(hb0, q0) + dot4(hb1, q1)) +
                                     (dot4(hb2, q2) + dot4(hb3, q3));
    }
}

__global__ __launch_bounds__(BLK) void gam_pred_direct(
    const float* __restrict__ out, const float* __restrict__ Wp,
    const float* __restrict__ bp, float* __restrict__ pred, int nsamp)
{
    int gid = blockIdx.x * BLK + threadIdx.x;
    int wave = gid >> 6, lane = gid & 63;
    int sub = lane >> 4, li = lane & 15;
    int s = wave * 4 + sub;
    if (s >= nsamp) return;
    float4 wv = ((const float4*)Wp)[li];
    float4 v = ((const float4*)(out + (size_t)s * DTOT))[li];
    float p = v.x * wv.x + v.y * wv.y + v.z * wv.z + v.w * wv.w;
    p += __shfl_xor(p, 1);
    p += __shfl_xor(p, 2);
    p += __shfl_xor(p, 4);
    p += __shfl_xor(p, 8);
    if (li == 0) pred[s] = p + bp[0];
}

extern "C" void kernel_launch(void* const* d_in, const int* in_sizes, int n_in,
                              void* d_out, int out_size, void* d_ws, size_t ws_size,
                              hipStream_t stream) {
    const float* x  = (const float*)d_in[0];
    const float* W1 = (const float*)d_in[1];
    const float* W2 = (const float*)d_in[2];
    const float* W3 = (const float*)d_in[3];
    const float* W4 = (const float*)d_in[4];
    const float* Wp = (const float*)d_in[5];
    const float* bp = (const float*)d_in[6];

    const int nsamp = in_sizes[0] / DTOT;   // 65536
    float* pred = (float*)d_out;            // (N,1) first
    float* outm = pred + nsamp;             // (N,64) second

    const size_t need = (size_t)2 * nsamp * DTOT * sizeof(float);
    if (ws_size >= need && (nsamp % (BLKM * 2)) == 0 && (nsamp % 64) == 0) {
        float* xt = (float*)d_ws;
        float* ot = xt + (size_t)nsamp * DTOT;
        transpose_in<<<dim3(nsamp / 64), dim3(256), 0, stream>>>(x, xt, nsamp);
        // nsamp/256 chunks x 64 features = 16384 blocks of 128 threads
        gam_main_s<<<dim3((nsamp / (BLKM * 2)) * 64), dim3(BLKM), 0, stream>>>(
            xt, W1, W2, W3, W4, ot, nsamp);
        finish<<<dim3(nsamp / 64), dim3(256), 0, stream>>>(
            ot, Wp, bp, outm, pred, nsamp);
    } else {
        int chunks = nsamp / (BLK * 2);
        gam_main_direct<<<dim3(chunks * 8), dim3(BLK), 0, stream>>>(
            x, W1, W2, W3, W4, outm, nsamp);
        int nthreads = (nsamp / 4) * 64;
        gam_pred_direct<<<dim3((nthreads + BLK - 1) / BLK), dim3(BLK), 0, stream>>>(
            outm, Wp, bp, pred, nsamp);
    }
}